// Round 21
// baseline (112.955 us; speedup 1.0000x reference)
//
#include <hip/hip_runtime.h>
#include <hip/hip_bf16.h>
#include <stdint.h>

typedef __bf16 bf16;
typedef __attribute__((ext_vector_type(8))) __bf16 bf16x8;
typedef __attribute__((ext_vector_type(4))) __bf16 bf16x4;
typedef __attribute__((ext_vector_type(4))) float f32x4;

#define NSEQ 1028
#define CDIM 1024
#define NHEADS 16
#define HD 64
#define BHN 64          // B*H
#define NPAD 1088       // 17*64
#define M_REAL 4112     // B*NSEQ
#define MTILES 33       // 33 m-tiles of 128 (last starts at M_REAL-128, overlap)

static __device__ __forceinline__ void async_copy16(bf16* lds, const bf16* g) {
  __builtin_amdgcn_global_load_lds(
      (const __attribute__((address_space(1))) uint32_t*)g,
      (__attribute__((address_space(3))) uint32_t*)lds, 16, 0, 0);
}

// ---- fused fp32 -> bf16 cast for all three inputs (1 launch) ------------
__global__ __launch_bounds__(256) void cast3_kernel(
    const float* __restrict__ s0, bf16* __restrict__ d0, long n0,
    const float* __restrict__ s1, bf16* __restrict__ d1, long n1,
    const float* __restrict__ s2, bf16* __restrict__ d2, long n2) {
  long total = n0 + n1 + n2;   // all multiples of 4
  long t = (long)blockIdx.x * 256 + threadIdx.x;
  long stride = (long)gridDim.x * 256;
  for (long j = t * 4; j < total; j += stride * 4) {
    const float* s; bf16* d; long jj = j;
    if (jj < n0) { s = s0; d = d0; }
    else if (jj < n0 + n1) { s = s1; d = d1; jj -= n0; }
    else { s = s2; d = d2; jj -= n0 + n1; }
    float4 v = *(const float4*)(s + jj);
    bf16x4 o;
    o[0] = (bf16)v.x; o[1] = (bf16)v.y; o[2] = (bf16)v.z; o[3] = (bf16)v.w;
    *(bf16x4*)(d + jj) = o;
  }
}

// ---- bf16 MFMA GEMM, 128m x BN, BK=32, dbuf, ONE barrier per step --------
// R21: step = { vmcnt(0); s_barrier; STAGE(t+1); ds_read; MFMA }.
// Race audit: (a) stage-visibility -- every wave drains its own stage(t)
// loads BEFORE the barrier, so post-barrier the whole tile is visible
// block-wide. (b) buffer reuse -- stage(t+1) (post-barrier-t) overwrites
// buf[(t+1)&1], read at step t-1; those ds_reads were consumed by step
// t-1's MFMAs (compiler lgkm waits precede MFMA issue) before any wave
// crossed barrier t. Halves barrier count vs R12 (32 vs 64) and removes
// the per-step lgkm drain; the vmcnt(0) drain is free since stage(t) was
// issued a full step (~3750cy >> L2 latency) earlier.
// Same tiles/swizzle/pinning/epilogues as verified R12.
template <int EPI, int NSTRIP, int BN>
__global__ __launch_bounds__(256, 4) void gemm_bf16_kernel(
    const bf16* __restrict__ A, const bf16* __restrict__ Bm,
    bf16* __restrict__ q_bf, bf16* __restrict__ k_bf, bf16* __restrict__ v_raw,
    float* __restrict__ outF,
    const float* __restrict__ cosb, const float* __restrict__ sinb,
    const float* __restrict__ nqw, const float* __restrict__ nkw) {
  constexpr int K = CDIM;
  constexpr int N = NSTRIP * 8 * BN;
  constexpr int HN = BN / 2;
  constexpr int NJ = HN / 16;
  constexpr int BSLOTS = (BN * 4) / 256;
  __shared__ __attribute__((aligned(16))) bf16 As[2][128 * 32];
  __shared__ __attribute__((aligned(16))) bf16 Bs[2][BN * 32];
  const int tid = threadIdx.x;
  const int lane = tid & 63;
  const int wid = tid >> 6;
  const int wr = wid >> 1, wc = wid & 1;
  const int l15 = lane & 15, l4 = lane >> 4;

  // XCD weight-pinning work mapping (R8)
  const int xcd = blockIdx.x & 7;
  const int pos = blockIdx.x >> 3;
  const int nloc = pos % NSTRIP;
  const int mi = pos / NSTRIP;
  const int n0 = (xcd * NSTRIP + nloc) * BN;
  const int m0 = (mi < MTILES - 1) ? (mi << 7) : (M_REAL - 128);

  f32x4 acc[4][NJ] = {};

  size_t a_base[2], b_base[BSLOTS];
#pragma unroll
  for (int s = 0; s < 2; s++) {
    int c = tid + s * 256;
    int u = c ^ ((c >> 3) & 7);
    a_base[s] = (size_t)(m0 + (u >> 2)) * K + ((u & 3) << 3);
  }
#pragma unroll
  for (int s = 0; s < BSLOTS; s++) {
    int c = tid + s * 256;
    int u = c ^ ((c >> 3) & 7);
    b_base[s] = (size_t)(n0 + (u >> 2)) * K + ((u & 3) << 3);
  }

#define STAGE(bufi, ktof)                                                   \
  {                                                                         \
    _Pragma("unroll")                                                       \
    for (int s = 0; s < 2; s++)                                             \
      async_copy16(&As[bufi][(tid + s * 256) * 8], A + a_base[s] + (ktof)); \
    _Pragma("unroll")                                                       \
    for (int s = 0; s < BSLOTS; s++)                                        \
      async_copy16(&Bs[bufi][(tid + s * 256) * 8], Bm + b_base[s] + (ktof));\
  }

  const int nt = K >> 5;   // 32 K-steps
  STAGE(0, 0);

  for (int t = 0; t < nt; ++t) {
    asm volatile("s_waitcnt vmcnt(0)" ::: "memory");   // own stage(t) landed
    __builtin_amdgcn_s_barrier();                      // tile t visible block-wide
    if (t + 1 < nt) STAGE((t + 1) & 1, (t + 1) << 5);  // safe: t-1 reads done

    const int cur = t & 1;
    bf16x8 af[4], bfr[NJ];
#pragma unroll
    for (int i = 0; i < 4; i++) {
      int u = ((wr * 64 + i * 16 + l15) << 2) | l4;
      af[i] = *(const bf16x8*)&As[cur][(u ^ ((u >> 3) & 7)) << 3];
    }
#pragma unroll
    for (int j = 0; j < NJ; j++) {
      int u = ((wc * HN + j * 16 + l15) << 2) | l4;
      bfr[j] = *(const bf16x8*)&Bs[cur][(u ^ ((u >> 3) & 7)) << 3];
    }

#pragma unroll
    for (int i = 0; i < 4; i++)
#pragma unroll
      for (int j = 0; j < NJ; j++)
        acc[i][j] = __builtin_amdgcn_mfma_f32_16x16x32_bf16(af[i], bfr[j], acc[i][j], 0, 0, 0);
  }
#undef STAGE

  if (EPI == 0) {
    const int d_base = n0 + wc * 64;
    const int tsel = d_base >> 10;
    const int hh = (d_base & 1023) >> 6;
    if (tsel == 2) {
#pragma unroll
      for (int i = 0; i < 4; i++)
#pragma unroll
        for (int r = 0; r < 4; r++) {
          int m = m0 + wr * 64 + i * 16 + l4 * 4 + r;
          int b = m / NSEQ, n = m % NSEQ;
          size_t rb = ((size_t)(b * NHEADS + hh) * NSEQ + n) * HD;
#pragma unroll
          for (int j = 0; j < NJ; j++)
            v_raw[rb + j * 16 + l15] = (bf16)acc[i][j][r];
        }
    } else {
      const float* wn = (tsel == 0) ? nqw : nkw;
      bf16* dst = (tsel == 0) ? q_bf : k_bf;
      float wv[NJ];
#pragma unroll
      for (int j = 0; j < NJ; j++) wv[j] = wn[j * 16 + l15];
#pragma unroll
      for (int i = 0; i < 4; i++)
#pragma unroll
        for (int r = 0; r < 4; r++) {
          int m = m0 + wr * 64 + i * 16 + l4 * 4 + r;
          float ss = 0.0f;
#pragma unroll
          for (int j = 0; j < NJ; j++) { float x = acc[i][j][r]; ss += x * x; }
          ss += __shfl_xor(ss, 1);
          ss += __shfl_xor(ss, 2);
          ss += __shfl_xor(ss, 4);
          ss += __shfl_xor(ss, 8);
          float rms = rsqrtf(ss * (1.0f / HD) + 1e-6f);
          int b = m / NSEQ, n = m % NSEQ;
          float qn[NJ];
#pragma unroll
          for (int j = 0; j < NJ; j++) qn[j] = acc[i][j][r] * rms * wv[j];
          size_t rb = ((size_t)(b * NHEADS + hh) * NPAD + n) * HD;
#pragma unroll
          for (int j = 0; j < NJ; j++) {
            float c = cosb[n * HD + j * 16 + l15];
            float s = sinb[n * HD + j * 16 + l15];
            float rot = (j < 2) ? -qn[j + 2] : qn[j - 2];
            dst[rb + j * 16 + l15] = (bf16)(qn[j] * c + rot * s);
          }
        }
    }
  } else {
#pragma unroll
    for (int i = 0; i < 4; i++)
#pragma unroll
      for (int j = 0; j < NJ; j++) {
        int d = n0 + wc * HN + j * 16 + l15;
        int mrow = m0 + wr * 64 + i * 16 + l4 * 4;
#pragma unroll
        for (int r = 0; r < 4; r++) {
          int m = mrow + r;
          outF[(size_t)m * N + d] = acc[i][j][r];
        }
      }
  }
}

// ---- V transpose: v_raw [bh][n][64] -> vT [bh][64][NPAD] patch-aligned ----
__global__ __launch_bounds__(256) void v_transpose_kernel(const bf16* __restrict__ v_raw,
                                                          bf16* __restrict__ vT) {
  __shared__ bf16 tile[64][65];
  int bh = blockIdx.y, c = blockIdx.x;
  int tid = threadIdx.x;
#pragma unroll
  for (int jj = 0; jj < 16; jj++) {
    int idx = tid + jj * 256;
    int i = idx >> 6, e = idx & 63;
    int n = (c == 0) ? i : (64 * c - 60 + i);
    bool ok = (c == 0) ? (i < 4) : (n < NSEQ);
    tile[i][e] = ok ? v_raw[((size_t)bh * NSEQ + n) * HD + e] : (bf16)0.0f;
  }
  __syncthreads();
#pragma unroll
  for (int jj = 0; jj < 16; jj++) {
    int idx = tid + jj * 256;
    int e = idx >> 6, i = idx & 63;
    vT[((size_t)bh * HD + e) * NPAD + 64 * c + i] = tile[i][e];
  }
}

// ------- masked flash attention, pipelined staging, ONE barrier/phase -----
// (R18 structure with the R21 single-barrier protocol; same race audit:
// P_s is wave-private, V ds_reads consumed by PV MFMAs before the wave
// reaches the next phase's barrier.)
__global__ __launch_bounds__(256) void attn_kernel(
    const bf16* __restrict__ Q, const bf16* __restrict__ Kb, const bf16* __restrict__ Vt,
    bf16* __restrict__ att, const int* __restrict__ winp) {
  __shared__ __attribute__((aligned(16))) bf16 P_s[4][16][72];
  __shared__ __attribute__((aligned(16))) bf16 KV[2][2][64 * 64];  // [buf][K,V]
  const int bh = blockIdx.y, qt = blockIdx.x;
  const int W = winp[0];
  const int tid = threadIdx.x, w = tid >> 6, lane = tid & 63;
  const int l15 = lane & 15, l4 = lane >> 4;
  const size_t qkbase = (size_t)bh * NPAD * HD;
  const size_t vtb = (size_t)bh * HD * NPAD;
  const bool is_spec = (qt == 16);
  const int b = bh >> 4, h = bh & 15;

  const int qrow0 = is_spec ? 0 : (4 + qt * 64 + w * 16);
  bf16x8 aq0 = *(const bf16x8*)&Q[qkbase + (size_t)(qrow0 + l15) * HD + l4 * 8];
  bf16x8 aq1 = *(const bf16x8*)&Q[qkbase + (size_t)(qrow0 + l15) * HD + 32 + l4 * 8];

  float mrow[4], lrow[4];
  f32x4 o[4] = {};
#pragma unroll
  for (int r = 0; r < 4; r++) { mrow[r] = -1e30f; lrow[r] = 0.0f; }

  if (!is_spec) {
    int ta = ((2 * qt - W + 64) >> 1) - 32;
    int tb = (2 * qt + 1 + W) >> 1;
    ta = ta < 0 ? 0 : ta;
    tb = tb > 15 ? 15 : tb;
    const int P = tb - ta + 2;   // phase 0 = specials tile, then ta..tb

    int srow[2], sch[2];
#pragma unroll
    for (int s = 0; s < 2; s++) {
      int c = tid + s * 256;
      int u = c ^ ((c >> 3) & 7);
      srow[s] = u >> 3; sch[s] = u & 7;
    }

#define STAGE_KV(bufi, p)                                                     \
    {                                                                         \
      int kr = (p) == 0 ? 0 : 4 + (ta + (p) - 1) * 64;                        \
      int vc = (p) == 0 ? 0 : 64 + (ta + (p) - 1) * 64;                       \
      _Pragma("unroll")                                                       \
      for (int s = 0; s < 2; s++)                                             \
        async_copy16(&KV[bufi][0][(tid + s * 256) * 8],                       \
                     Kb + qkbase + (size_t)(kr + srow[s]) * HD + sch[s] * 8); \
      _Pragma("unroll")                                                       \
      for (int s = 0; s < 2; s++)                                             \
        async_copy16(&KV[bufi][1][(tid + s * 256) * 8],                       \
                     Vt + vtb + (size_t)srow[s] * NPAD + vc + sch[s] * 8);    \
    }

    STAGE_KV(0, 0);

    for (int p = 0; p < P; ++p) {
      asm volatile("s_waitcnt vmcnt(0)" ::: "memory");   // own stage(p) landed
      __builtin_amdgcn_s_barrier();                      // tile p visible
      if (p + 1 < P) STAGE_KV((p + 1) & 1, p + 1);       // safe: p-1 reads done

      const int cur = p & 1;
      const bool sp = (p == 0);
      const int tau = ta + p - 1;

      f32x4 sacc[4] = {};
#pragma unroll
      for (int kf = 0; kf < 4; kf++) {
        int u0 = ((kf * 16 + l15) << 3) | l4;
        int u1 = ((kf * 16 + l15) << 3) | (4 + l4);
        bf16x8 b0 = *(const bf16x8*)&KV[cur][0][(u0 ^ ((u0 >> 3) & 7)) << 3];
        bf16x8 b1 = *(const bf16x8*)&KV[cur][0][(u1 ^ ((u1 >> 3) & 7)) << 3];
        sacc[kf] = __builtin_amdgcn_mfma_f32_16x16x32_bf16(aq0, b0, sacc[kf], 0, 0, 0);
        sacc[kf] = __builtin_amdgcn_mfma_f32_16x16x32_bf16(aq1, b1, sacc[kf], 0, 0, 0);
      }

      float pvv[4][4];
#pragma unroll
      for (int kf = 0; kf < 4; kf++)
#pragma unroll
        for (int r = 0; r < 4; r++) {
          float s = sacc[kf][r] * 0.125f;
          bool valid;
          if (sp) {
            valid = (kf == 0) && (l15 < 4);
          } else {
            int p_k = tau * 64 + kf * 16 + l15;
            int p_q = qt * 64 + w * 16 + l4 * 4 + r;
            int dr = (p_q >> 5) - (p_k >> 5); dr = dr < 0 ? -dr : dr;
            int dc = (p_q & 31) - (p_k & 31); dc = dc < 0 ? -dc : dc;
            valid = (dr <= W) && (dc <= W);
          }
          pvv[kf][r] = valid ? s : -1e30f;
        }

#pragma unroll
      for (int r = 0; r < 4; r++) {
        float mx = fmaxf(fmaxf(pvv[0][r], pvv[1][r]), fmaxf(pvv[2][r], pvv[3][r]));
#pragma unroll
        for (int mm = 1; mm < 16; mm <<= 1) mx = fmaxf(mx, __shfl_xor(mx, mm));
        float mnew = fmaxf(mrow[r], mx);
        float scale = __expf(mrow[r] - mnew);
        float rs = 0.0f;
#pragma unroll
        for (int kf = 0; kf < 4; kf++) {
          float pp = __expf(pvv[kf][r] - mnew);
          pvv[kf][r] = pp;
          rs += pp;
        }
#pragma unroll
        for (int mm = 1; mm < 16; mm <<= 1) rs += __shfl_xor(rs, mm);
        lrow[r] = lrow[r] * scale + rs;
        mrow[r] = mnew;
#pragma unroll
        for (int f = 0; f < 4; f++) o[f][r] *= scale;
      }

#pragma unroll
      for (int kf = 0; kf < 4; kf++)
#pragma unroll
        for (int r = 0; r < 4; r++)
          P_s[w][l4 * 4 + r][kf * 16 + l15] = (bf16)pvv[kf][r];

      bf16x8 pa0 = *(const bf16x8*)&P_s[w][l15][l4 * 8];
      bf16x8 pa1 = *(const bf16x8*)&P_s[w][l15][32 + l4 * 8];
#pragma unroll
      for (int f = 0; f < 4; f++) {
        int u0 = ((f * 16 + l15) << 3) | l4;
        int u1 = ((f * 16 + l15) << 3) | (4 + l4);
        bf16x8 v0 = *(const bf16x8*)&KV[cur][1][(u0 ^ ((u0 >> 3) & 7)) << 3];
        bf16x8 v1 = *(const bf16x8*)&KV[cur][1][(u1 ^ ((u1 >> 3) & 7)) << 3];
        o[f] = __builtin_amdgcn_mfma_f32_16x16x32_bf16(pa0, v0, o[f], 0, 0, 0);
        o[f] = __builtin_amdgcn_mfma_f32_16x16x32_bf16(pa1, v1, o[f], 0, 0, 0);
      }
    }
#undef STAGE_KV

#pragma unroll
    for (int f = 0; f < 4; f++)
#pragma unroll
      for (int r = 0; r < 4; r++) {
        int n = qrow0 + l4 * 4 + r;
        att[((size_t)(b * NSEQ + n)) * CDIM + h * HD + f * 16 + l15] =
            (bf16)(o[f][r] / lrow[r]);
      }
  } else {
    // spec path: 4 special q rows, 17 key tiles strided over waves;
    // direct global loads (tail, 64 blocks). Merge buffers overlay KV.
    float* o_sf = (float*)&KV[0][0][0];    // [4][4][64] floats
    float* ml_sf = o_sf + 4 * 4 * 64;      // [4][2][16] floats

    for (int p = w; p <= 16; p += 4) {
      const bool sp = (p == 0);
      const int tau = p - 1;
      const int krow0 = sp ? 0 : (4 + tau * 64);
      const int vcol0 = sp ? 0 : (64 + tau * 64);

      f32x4 sacc[4] = {};
#pragma unroll
      for (int kf = 0; kf < 4; kf++) {
        const bf16* kp = &Kb[qkbase + (size_t)(krow0 + kf * 16 + l15) * HD];
        bf16x8 b0 = *(const bf16x8*)(kp + l4 * 8);
        bf16x8 b1 = *(const bf16x8*)(kp + 32 + l4 * 8);
        sacc[kf] = __builtin_amdgcn_mfma_f32_16x16x32_bf16(aq0, b0, sacc[kf], 0, 0, 0);
        sacc[kf] = __builtin_amdgcn_mfma_f32_16x16x32_bf16(aq1, b1, sacc[kf], 0, 0, 0);
      }

      float pvv[4][4];
#pragma unroll
      for (int kf = 0; kf < 4; kf++)
#pragma unroll
        for (int r = 0; r < 4; r++) {
          float s = sacc[kf][r] * 0.125f;
          bool valid = sp ? ((kf == 0) && (l15 < 4)) : true;
          pvv[kf][r] = valid ? s : -1e30f;
        }

#pragma unroll
      for (int r = 0; r < 4; r++) {
        float mx = fmaxf(fmaxf(pvv[0][r], pvv[1][r]), fmaxf(pvv[2][r], pvv[3][r]));
#pragma unroll
        for (int mm = 1; mm < 16; mm <<= 1) mx = fmaxf(mx, __shfl_xor(mx, mm));
        float mnew = fmaxf(mrow[r], mx);
        float scale = __expf(mrow[r] - mnew);
        float rs = 0.0f;
#pragma unroll
        for (int kf = 0; kf < 4; kf++) {
          float pp = __expf(pvv[kf][r] - mnew);
          pvv[kf][r] = pp;
          rs += pp;
        }
#pragma unroll
        for (int mm = 1; mm < 16; mm <<= 1) rs += __shfl_xor(rs, mm);
        lrow[r] = lrow[r] * scale + rs;
        mrow[r] = mnew;
#pragma unroll
        for (int f = 0; f < 4; f++) o[f][r] *= scale;
      }

#pragma unroll
      for (int kf = 0; kf < 4; kf++)
#pragma unroll
        for (int r = 0; r < 4; r++)
          P_s[w][l4 * 4 + r][kf * 16 + l15] = (bf16)pvv[kf][r];

      bf16x8 pa0 = *(const bf16x8*)&P_s[w][l15][l4 * 8];
      bf16x8 pa1 = *(const bf16x8*)&P_s[w][l15][32 + l4 * 8];
#pragma unroll
      for (int f = 0; f < 4; f++) {
        const bf16* vp = &Vt[vtb + (size_t)(f * 16 + l15) * NPAD + vcol0];
        bf16x8 v0 = *(const bf16x8*)(vp + l4 * 8);
        bf16x8 v1 = *(const bf16x8*)(vp + 32 + l4 * 8);
        o[f] = __builtin_amdgcn_mfma_f32_16x16x32_bf16(pa0, v0, o[f], 0, 0, 0);
        o[f] = __builtin_amdgcn_mfma_f32_16x16x32_bf16(pa1, v1, o[f], 0, 0, 0);
      }
    }

    if (l4 == 0) {
#pragma unroll
      for (int f = 0; f < 4; f++)
#pragma unroll
        for (int r = 0; r < 4; r++) o_sf[(w * 4 + r) * 64 + f * 16 + l15] = o[f][r];
      if (l15 == 0)
#pragma unroll
        for (int r = 0; r < 4; r++) {
          ml_sf[(w * 2 + 0) * 16 + r] = mrow[r];
          ml_sf[(w * 2 + 1) * 16 + r] = lrow[r];
        }
    }
    __syncthreads();
    int row = tid >> 6, dim = tid & 63;
    float M = -1e30f;
#pragma unroll
    for (int ww = 0; ww < 4; ww++) M = fmaxf(M, ml_sf[(ww * 2) * 16 + row]);
    float L = 0.0f, val = 0.0f;
#pragma unroll
    for (int ww = 0; ww < 4; ww++) {
      float e = __expf(ml_sf[(ww * 2) * 16 + row] - M);
      L += e * ml_sf[(ww * 2 + 1) * 16 + row];
      val += e * o_sf[(ww * 4 + row) * 64 + dim];
    }
    att[((size_t)(b * NSEQ + row)) * CDIM + h * HD + dim] = (bf16)(val / L);
  }
}

// ------------------------------------------------------------------------
extern "C" void kernel_launch(void* const* d_in, const int* in_sizes, int n_in,
                              void* d_out, int out_size, void* d_ws, size_t ws_size,
                              hipStream_t stream) {
  const float* hidden = (const float*)d_in[0];
  const float* cosb = (const float*)d_in[1];
  const float* sinb = (const float*)d_in[2];
  const float* qkv_w = (const float*)d_in[3];
  const float* out_w = (const float*)d_in[4];
  const float* norm_q_w = (const float*)d_in[5];
  const float* norm_k_w = (const float*)d_in[6];
  const int* win = (const int*)d_in[7];
  float* out = (float*)d_out;

  char* ws = (char*)d_ws;
  size_t off = 0;
  auto alloc = [&](size_t bytes) {
    char* p = ws + off;
    off += (bytes + 255) & ~(size_t)255;
    return p;
  };
  bf16* A_bf  = (bf16*)alloc((size_t)M_REAL * CDIM * 2);
  bf16* W1    = (bf16*)alloc((size_t)3 * CDIM * CDIM * 2);
  bf16* W2    = (bf16*)alloc((size_t)CDIM * CDIM * 2);
  bf16* v_raw = (bf16*)alloc((size_t)BHN * NSEQ * HD * 2);
  bf16* q_bf  = (bf16*)alloc((size_t)BHN * NPAD * HD * 2);
  bf16* k_bf  = (bf16*)alloc((size_t)BHN * NPAD * HD * 2);
  bf16* vT    = (bf16*)alloc((size_t)BHN * HD * NPAD * 2);
  bf16* att   = (bf16*)alloc((size_t)M_REAL * CDIM * 2);
  (void)ws_size; (void)in_sizes; (void)n_in; (void)out_size;

  cast3_kernel<<<2048, 256, 0, stream>>>(
      hidden, A_bf, (long)M_REAL * CDIM,
      qkv_w, W1, (long)3 * CDIM * CDIM,
      out_w, W2, (long)CDIM * CDIM);

  // GEMM1: 792 blocks, BN=128; W1 strip L2-pinned/XCD; 1-barrier protocol.
  gemm_bf16_kernel<0, 3, 128><<<792, 256, 0, stream>>>(
      A_bf, W1, q_bf, k_bf, v_raw, nullptr, cosb, sinb, norm_q_w, norm_k_w);
  v_transpose_kernel<<<dim3(17, 64), 256, 0, stream>>>(v_raw, vT);
  // attn: 64 q-rows/block, 17 x 64 = 1088 blocks; 1-barrier protocol.
  attn_kernel<<<dim3(17, 64), 256, 0, stream>>>(q_bf, k_bf, vT, att, win);
  // GEMM2: 528 blocks, BN=64; W2 strip L2-pinned/XCD; 1-barrier protocol.
  gemm_bf16_kernel<1, 2, 64><<<528, 256, 0, stream>>>(
      att, W2, nullptr, nullptr, nullptr, out, nullptr, nullptr, nullptr, nullptr);
}

// Round 22
// 109.896 us; speedup vs baseline: 1.0278x; 1.0278x over previous
//
#include <hip/hip_runtime.h>
#include <hip/hip_bf16.h>
#include <stdint.h>

typedef __bf16 bf16;
typedef __attribute__((ext_vector_type(8))) __bf16 bf16x8;
typedef __attribute__((ext_vector_type(4))) __bf16 bf16x4;
typedef __attribute__((ext_vector_type(4))) float f32x4;

#define NSEQ 1028
#define CDIM 1024
#define NHEADS 16
#define HD 64
#define BHN 64          // B*H
#define NPAD 1088       // 17*64
#define M_REAL 4112     // B*NSEQ
#define MTILES 33       // 33 m-tiles of 128 (last starts at M_REAL-128, overlap)

static __device__ __forceinline__ void async_copy16(bf16* lds, const bf16* g) {
  __builtin_amdgcn_global_load_lds(
      (const __attribute__((address_space(1))) uint32_t*)g,
      (__attribute__((address_space(3))) uint32_t*)lds, 16, 0, 0);
}

// ---- fused fp32 -> bf16 cast for all three inputs (1 launch) ------------
__global__ __launch_bounds__(256) void cast3_kernel(
    const float* __restrict__ s0, bf16* __restrict__ d0, long n0,
    const float* __restrict__ s1, bf16* __restrict__ d1, long n1,
    const float* __restrict__ s2, bf16* __restrict__ d2, long n2) {
  long total = n0 + n1 + n2;   // all multiples of 4
  long t = (long)blockIdx.x * 256 + threadIdx.x;
  long stride = (long)gridDim.x * 256;
  for (long j = t * 4; j < total; j += stride * 4) {
    const float* s; bf16* d; long jj = j;
    if (jj < n0) { s = s0; d = d0; }
    else if (jj < n0 + n1) { s = s1; d = d1; jj -= n0; }
    else { s = s2; d = d2; jj -= n0 + n1; }
    float4 v = *(const float4*)(s + jj);
    bf16x4 o;
    o[0] = (bf16)v.x; o[1] = (bf16)v.y; o[2] = (bf16)v.z; o[3] = (bf16)v.w;
    *(bf16x4*)(d + jj) = o;
  }
}

// ---- bf16 MFMA GEMM, 128m x BN, BK=32, DEPTH-deep LDS pipeline -----------
// (verified R15 template; DEPTH=1 for both = exact R12 configs)
template <int EPI, int NSTRIP, int BN, int DEPTH>
__global__ __launch_bounds__(256, 4) void gemm_bf16_kernel(
    const bf16* __restrict__ A, const bf16* __restrict__ Bm,
    bf16* __restrict__ q_bf, bf16* __restrict__ k_bf, bf16* __restrict__ v_raw,
    float* __restrict__ outF,
    const float* __restrict__ cosb, const float* __restrict__ sinb,
    const float* __restrict__ nqw, const float* __restrict__ nkw) {
  constexpr int K = CDIM;
  constexpr int N = NSTRIP * 8 * BN;
  constexpr int HN = BN / 2;
  constexpr int NJ = HN / 16;
  constexpr int BSLOTS = (BN * 4) / 256;
  constexpr int LPS = 2 + BSLOTS;
  constexpr int NBUF = DEPTH + 1;
  __shared__ __attribute__((aligned(16))) bf16 As[NBUF][128 * 32];
  __shared__ __attribute__((aligned(16))) bf16 Bs[NBUF][BN * 32];
  const int tid = threadIdx.x;
  const int lane = tid & 63;
  const int wid = tid >> 6;
  const int wr = wid >> 1, wc = wid & 1;
  const int l15 = lane & 15, l4 = lane >> 4;

  const int xcd = blockIdx.x & 7;
  const int pos = blockIdx.x >> 3;
  const int nloc = pos % NSTRIP;
  const int mi = pos / NSTRIP;
  const int n0 = (xcd * NSTRIP + nloc) * BN;
  const int m0 = (mi < MTILES - 1) ? (mi << 7) : (M_REAL - 128);

  f32x4 acc[4][NJ] = {};

  size_t a_base[2], b_base[BSLOTS];
#pragma unroll
  for (int s = 0; s < 2; s++) {
    int c = tid + s * 256;
    int u = c ^ ((c >> 3) & 7);
    a_base[s] = (size_t)(m0 + (u >> 2)) * K + ((u & 3) << 3);
  }
#pragma unroll
  for (int s = 0; s < BSLOTS; s++) {
    int c = tid + s * 256;
    int u = c ^ ((c >> 3) & 7);
    b_base[s] = (size_t)(n0 + (u >> 2)) * K + ((u & 3) << 3);
  }

#define STAGE(bufi, ktof)                                                   \
  {                                                                         \
    _Pragma("unroll")                                                       \
    for (int s = 0; s < 2; s++)                                             \
      async_copy16(&As[bufi][(tid + s * 256) * 8], A + a_base[s] + (ktof)); \
    _Pragma("unroll")                                                       \
    for (int s = 0; s < BSLOTS; s++)                                        \
      async_copy16(&Bs[bufi][(tid + s * 256) * 8], Bm + b_base[s] + (ktof));\
  }

  const int nt = K >> 5;
#pragma unroll
  for (int d = 0; d < DEPTH; d++) STAGE(d, d << 5);

  for (int t = 0; t < nt; ++t) {
    if (t + DEPTH < nt) STAGE((t + DEPTH) % NBUF, (t + DEPTH) << 5);
    const int left = nt - 1 - t;
    if (left >= DEPTH) {
      asm volatile("s_waitcnt vmcnt(%0)" :: "i"(DEPTH * LPS) : "memory");
    } else if (left == 1) {
      asm volatile("s_waitcnt vmcnt(%0)" :: "i"(LPS) : "memory");
    } else {
      asm volatile("s_waitcnt vmcnt(0)" ::: "memory");
    }
    __builtin_amdgcn_s_barrier();

    const int cur = t % NBUF;
    bf16x8 af[4], bfr[NJ];
#pragma unroll
    for (int i = 0; i < 4; i++) {
      int u = ((wr * 64 + i * 16 + l15) << 2) | l4;
      af[i] = *(const bf16x8*)&As[cur][(u ^ ((u >> 3) & 7)) << 3];
    }
#pragma unroll
    for (int j = 0; j < NJ; j++) {
      int u = ((wc * HN + j * 16 + l15) << 2) | l4;
      bfr[j] = *(const bf16x8*)&Bs[cur][(u ^ ((u >> 3) & 7)) << 3];
    }

#pragma unroll
    for (int i = 0; i < 4; i++)
#pragma unroll
      for (int j = 0; j < NJ; j++)
        acc[i][j] = __builtin_amdgcn_mfma_f32_16x16x32_bf16(af[i], bfr[j], acc[i][j], 0, 0, 0);

    asm volatile("s_waitcnt lgkmcnt(0)" ::: "memory");
    __builtin_amdgcn_s_barrier();
  }
#undef STAGE

  if (EPI == 0) {
    const int d_base = n0 + wc * 64;
    const int tsel = d_base >> 10;
    const int hh = (d_base & 1023) >> 6;
    if (tsel == 2) {
#pragma unroll
      for (int i = 0; i < 4; i++)
#pragma unroll
        for (int r = 0; r < 4; r++) {
          int m = m0 + wr * 64 + i * 16 + l4 * 4 + r;
          int b = m / NSEQ, n = m % NSEQ;
          size_t rb = ((size_t)(b * NHEADS + hh) * NSEQ + n) * HD;
#pragma unroll
          for (int j = 0; j < NJ; j++)
            v_raw[rb + j * 16 + l15] = (bf16)acc[i][j][r];
        }
    } else {
      const float* wn = (tsel == 0) ? nqw : nkw;
      bf16* dst = (tsel == 0) ? q_bf : k_bf;
      float wv[NJ];
#pragma unroll
      for (int j = 0; j < NJ; j++) wv[j] = wn[j * 16 + l15];
#pragma unroll
      for (int i = 0; i < 4; i++)
#pragma unroll
        for (int r = 0; r < 4; r++) {
          int m = m0 + wr * 64 + i * 16 + l4 * 4 + r;
          float ss = 0.0f;
#pragma unroll
          for (int j = 0; j < NJ; j++) { float x = acc[i][j][r]; ss += x * x; }
          ss += __shfl_xor(ss, 1);
          ss += __shfl_xor(ss, 2);
          ss += __shfl_xor(ss, 4);
          ss += __shfl_xor(ss, 8);
          float rms = rsqrtf(ss * (1.0f / HD) + 1e-6f);
          int b = m / NSEQ, n = m % NSEQ;
          float qn[NJ];
#pragma unroll
          for (int j = 0; j < NJ; j++) qn[j] = acc[i][j][r] * rms * wv[j];
          size_t rb = ((size_t)(b * NHEADS + hh) * NPAD + n) * HD;
#pragma unroll
          for (int j = 0; j < NJ; j++) {
            float c = cosb[n * HD + j * 16 + l15];
            float s = sinb[n * HD + j * 16 + l15];
            float rot = (j < 2) ? -qn[j + 2] : qn[j - 2];
            dst[rb + j * 16 + l15] = (bf16)(qn[j] * c + rot * s);
          }
        }
    }
  } else {
#pragma unroll
    for (int i = 0; i < 4; i++)
#pragma unroll
      for (int j = 0; j < NJ; j++) {
        int d = n0 + wc * HN + j * 16 + l15;
        int mrow = m0 + wr * 64 + i * 16 + l4 * 4;
#pragma unroll
        for (int r = 0; r < 4; r++) {
          int m = mrow + r;
          outF[(size_t)m * N + d] = acc[i][j][r];
        }
      }
  }
}

// ---- V transpose: v_raw [bh][n][64] -> vT [bh][64][NPAD] patch-aligned ----
__global__ __launch_bounds__(256) void v_transpose_kernel(const bf16* __restrict__ v_raw,
                                                          bf16* __restrict__ vT) {
  __shared__ bf16 tile[64][65];
  int bh = blockIdx.y, c = blockIdx.x;
  int tid = threadIdx.x;
#pragma unroll
  for (int jj = 0; jj < 16; jj++) {
    int idx = tid + jj * 256;
    int i = idx >> 6, e = idx & 63;
    int n = (c == 0) ? i : (64 * c - 60 + i);
    bool ok = (c == 0) ? (i < 4) : (n < NSEQ);
    tile[i][e] = ok ? v_raw[((size_t)bh * NSEQ + n) * HD + e] : (bf16)0.0f;
  }
  __syncthreads();
#pragma unroll
  for (int jj = 0; jj < 16; jj++) {
    int idx = tid + jj * 256;
    int e = idx >> 6, i = idx & 63;
    vT[((size_t)bh * HD + e) * NPAD + 64 * c + i] = tile[i][e];
  }
}

// ---------------- masked flash attention, pipelined K/V staging -----------
// R22 = R18 (verified 110.0us) + SLIM SPECIALS PHASE: phase 0 has valid
// keys only at kf==0, l15<4 (4 special keys). pvv for kf>=1 is -inf -> P=0,
// so skip their QK MFMAs (8->2/wave) and the pa1 PV half (keys 32-63, all
// zero P; 8->4/wave). P_s still gets zeros for keys 16-31, so pa0's read
// (keys 0-31) stays correct. Branches are block-uniform.
__global__ __launch_bounds__(256) void attn_kernel(
    const bf16* __restrict__ Q, const bf16* __restrict__ Kb, const bf16* __restrict__ Vt,
    bf16* __restrict__ att, const int* __restrict__ winp) {
  __shared__ __attribute__((aligned(16))) bf16 P_s[4][16][72];
  __shared__ __attribute__((aligned(16))) bf16 KV[2][2][64 * 64];  // [buf][K,V]
  const int bh = blockIdx.y, qt = blockIdx.x;
  const int W = winp[0];
  const int tid = threadIdx.x, w = tid >> 6, lane = tid & 63;
  const int l15 = lane & 15, l4 = lane >> 4;
  const size_t qkbase = (size_t)bh * NPAD * HD;
  const size_t vtb = (size_t)bh * HD * NPAD;
  const bool is_spec = (qt == 16);
  const int b = bh >> 4, h = bh & 15;

  const int qrow0 = is_spec ? 0 : (4 + qt * 64 + w * 16);
  bf16x8 aq0 = *(const bf16x8*)&Q[qkbase + (size_t)(qrow0 + l15) * HD + l4 * 8];
  bf16x8 aq1 = *(const bf16x8*)&Q[qkbase + (size_t)(qrow0 + l15) * HD + 32 + l4 * 8];

  float mrow[4], lrow[4];
  f32x4 o[4] = {};
#pragma unroll
  for (int r = 0; r < 4; r++) { mrow[r] = -1e30f; lrow[r] = 0.0f; }

  if (!is_spec) {
    int ta = ((2 * qt - W + 64) >> 1) - 32;
    int tb = (2 * qt + 1 + W) >> 1;
    ta = ta < 0 ? 0 : ta;
    tb = tb > 15 ? 15 : tb;
    const int P = tb - ta + 2;   // phase 0 = specials tile, then ta..tb

    int srow[2], sch[2];
#pragma unroll
    for (int s = 0; s < 2; s++) {
      int c = tid + s * 256;
      int u = c ^ ((c >> 3) & 7);
      srow[s] = u >> 3; sch[s] = u & 7;
    }

#define STAGE_KV(bufi, p)                                                     \
    {                                                                         \
      int kr = (p) == 0 ? 0 : 4 + (ta + (p) - 1) * 64;                        \
      int vc = (p) == 0 ? 0 : 64 + (ta + (p) - 1) * 64;                       \
      _Pragma("unroll")                                                       \
      for (int s = 0; s < 2; s++)                                             \
        async_copy16(&KV[bufi][0][(tid + s * 256) * 8],                       \
                     Kb + qkbase + (size_t)(kr + srow[s]) * HD + sch[s] * 8); \
      _Pragma("unroll")                                                       \
      for (int s = 0; s < 2; s++)                                             \
        async_copy16(&KV[bufi][1][(tid + s * 256) * 8],                       \
                     Vt + vtb + (size_t)srow[s] * NPAD + vc + sch[s] * 8);    \
    }

    STAGE_KV(0, 0);

    for (int p = 0; p < P; ++p) {
      if (p + 1 < P) {
        STAGE_KV((p + 1) & 1, p + 1);
        asm volatile("s_waitcnt vmcnt(4)" ::: "memory");  // phase p landed
      } else {
        asm volatile("s_waitcnt vmcnt(0)" ::: "memory");
      }
      __builtin_amdgcn_s_barrier();  // raw: phase p+1 stays in flight

      const int cur = p & 1;
      const bool sp = (p == 0);
      const int tau = ta + p - 1;

      float pvv[4][4];
      if (sp) {
        // specials: only kf==0 fragment has valid keys (l15<4)
        f32x4 s0acc = {};
        {
          int u0 = (l15 << 3) | l4;
          int u1 = (l15 << 3) | (4 + l4);
          bf16x8 b0 = *(const bf16x8*)&KV[cur][0][(u0 ^ ((u0 >> 3) & 7)) << 3];
          bf16x8 b1 = *(const bf16x8*)&KV[cur][0][(u1 ^ ((u1 >> 3) & 7)) << 3];
          s0acc = __builtin_amdgcn_mfma_f32_16x16x32_bf16(aq0, b0, s0acc, 0, 0, 0);
          s0acc = __builtin_amdgcn_mfma_f32_16x16x32_bf16(aq1, b1, s0acc, 0, 0, 0);
        }
#pragma unroll
        for (int r = 0; r < 4; r++) {
          pvv[0][r] = (l15 < 4) ? s0acc[r] * 0.125f : -1e30f;
          pvv[1][r] = -1e30f; pvv[2][r] = -1e30f; pvv[3][r] = -1e30f;
        }
      } else {
        f32x4 sacc[4] = {};
#pragma unroll
        for (int kf = 0; kf < 4; kf++) {
          int u0 = ((kf * 16 + l15) << 3) | l4;
          int u1 = ((kf * 16 + l15) << 3) | (4 + l4);
          bf16x8 b0 = *(const bf16x8*)&KV[cur][0][(u0 ^ ((u0 >> 3) & 7)) << 3];
          bf16x8 b1 = *(const bf16x8*)&KV[cur][0][(u1 ^ ((u1 >> 3) & 7)) << 3];
          sacc[kf] = __builtin_amdgcn_mfma_f32_16x16x32_bf16(aq0, b0, sacc[kf], 0, 0, 0);
          sacc[kf] = __builtin_amdgcn_mfma_f32_16x16x32_bf16(aq1, b1, sacc[kf], 0, 0, 0);
        }
#pragma unroll
        for (int kf = 0; kf < 4; kf++)
#pragma unroll
          for (int r = 0; r < 4; r++) {
            float s = sacc[kf][r] * 0.125f;
            int p_k = tau * 64 + kf * 16 + l15;
            int p_q = qt * 64 + w * 16 + l4 * 4 + r;
            int dr = (p_q >> 5) - (p_k >> 5); dr = dr < 0 ? -dr : dr;
            int dc = (p_q & 31) - (p_k & 31); dc = dc < 0 ? -dc : dc;
            pvv[kf][r] = ((dr <= W) && (dc <= W)) ? s : -1e30f;
          }
      }

#pragma unroll
      for (int r = 0; r < 4; r++) {
        float mx = fmaxf(fmaxf(pvv[0][r], pvv[1][r]), fmaxf(pvv[2][r], pvv[3][r]));
#pragma unroll
        for (int mm = 1; mm < 16; mm <<= 1) mx = fmaxf(mx, __shfl_xor(mx, mm));
        float mnew = fmaxf(mrow[r], mx);
        float scale = __expf(mrow[r] - mnew);
        float rs = 0.0f;
#pragma unroll
        for (int kf = 0; kf < 4; kf++) {
          float pp = __expf(pvv[kf][r] - mnew);
          pvv[kf][r] = pp;
          rs += pp;
        }
#pragma unroll
        for (int mm = 1; mm < 16; mm <<= 1) rs += __shfl_xor(rs, mm);
        lrow[r] = lrow[r] * scale + rs;
        mrow[r] = mnew;
#pragma unroll
        for (int f = 0; f < 4; f++) o[f][r] *= scale;
      }

#pragma unroll
      for (int kf = 0; kf < 4; kf++)
#pragma unroll
        for (int r = 0; r < 4; r++)
          P_s[w][l4 * 4 + r][kf * 16 + l15] = (bf16)pvv[kf][r];

      bf16x8 pa0 = *(const bf16x8*)&P_s[w][l15][l4 * 8];
      if (sp) {
        // only keys 0-31 can have nonzero P (actually 0-3): pa0 half only
#pragma unroll
        for (int f = 0; f < 4; f++) {
          int u0 = ((f * 16 + l15) << 3) | l4;
          bf16x8 v0 = *(const bf16x8*)&KV[cur][1][(u0 ^ ((u0 >> 3) & 7)) << 3];
          o[f] = __builtin_amdgcn_mfma_f32_16x16x32_bf16(pa0, v0, o[f], 0, 0, 0);
        }
      } else {
        bf16x8 pa1 = *(const bf16x8*)&P_s[w][l15][32 + l4 * 8];
#pragma unroll
        for (int f = 0; f < 4; f++) {
          int u0 = ((f * 16 + l15) << 3) | l4;
          int u1 = ((f * 16 + l15) << 3) | (4 + l4);
          bf16x8 v0 = *(const bf16x8*)&KV[cur][1][(u0 ^ ((u0 >> 3) & 7)) << 3];
          bf16x8 v1 = *(const bf16x8*)&KV[cur][1][(u1 ^ ((u1 >> 3) & 7)) << 3];
          o[f] = __builtin_amdgcn_mfma_f32_16x16x32_bf16(pa0, v0, o[f], 0, 0, 0);
          o[f] = __builtin_amdgcn_mfma_f32_16x16x32_bf16(pa1, v1, o[f], 0, 0, 0);
        }
      }

      asm volatile("s_waitcnt lgkmcnt(0)" ::: "memory");  // KV[cur] reads done
      __builtin_amdgcn_s_barrier();
    }
#undef STAGE_KV

#pragma unroll
    for (int f = 0; f < 4; f++)
#pragma unroll
      for (int r = 0; r < 4; r++) {
        int n = qrow0 + l4 * 4 + r;
        att[((size_t)(b * NSEQ + n)) * CDIM + h * HD + f * 16 + l15] =
            (bf16)(o[f][r] / lrow[r]);
      }
  } else {
    // spec path: 4 special q rows, 17 key tiles strided over waves;
    // direct global loads (tail, 64 blocks). Merge buffers overlay KV.
    float* o_sf = (float*)&KV[0][0][0];    // [4][4][64] floats
    float* ml_sf = o_sf + 4 * 4 * 64;      // [4][2][16] floats

    for (int p = w; p <= 16; p += 4) {
      const bool sp = (p == 0);
      const int tau = p - 1;
      const int krow0 = sp ? 0 : (4 + tau * 64);
      const int vcol0 = sp ? 0 : (64 + tau * 64);

      f32x4 sacc[4] = {};
#pragma unroll
      for (int kf = 0; kf < 4; kf++) {
        const bf16* kp = &Kb[qkbase + (size_t)(krow0 + kf * 16 + l15) * HD];
        bf16x8 b0 = *(const bf16x8*)(kp + l4 * 8);
        bf16x8 b1 = *(const bf16x8*)(kp + 32 + l4 * 8);
        sacc[kf] = __builtin_amdgcn_mfma_f32_16x16x32_bf16(aq0, b0, sacc[kf], 0, 0, 0);
        sacc[kf] = __builtin_amdgcn_mfma_f32_16x16x32_bf16(aq1, b1, sacc[kf], 0, 0, 0);
      }

      float pvv[4][4];
#pragma unroll
      for (int kf = 0; kf < 4; kf++)
#pragma unroll
        for (int r = 0; r < 4; r++) {
          float s = sacc[kf][r] * 0.125f;
          bool valid = sp ? ((kf == 0) && (l15 < 4)) : true;
          pvv[kf][r] = valid ? s : -1e30f;
        }

#pragma unroll
      for (int r = 0; r < 4; r++) {
        float mx = fmaxf(fmaxf(pvv[0][r], pvv[1][r]), fmaxf(pvv[2][r], pvv[3][r]));
#pragma unroll
        for (int mm = 1; mm < 16; mm <<= 1) mx = fmaxf(mx, __shfl_xor(mx, mm));
        float mnew = fmaxf(mrow[r], mx);
        float scale = __expf(mrow[r] - mnew);
        float rs = 0.0f;
#pragma unroll
        for (int kf = 0; kf < 4; kf++) {
          float pp = __expf(pvv[kf][r] - mnew);
          pvv[kf][r] = pp;
          rs += pp;
        }
#pragma unroll
        for (int mm = 1; mm < 16; mm <<= 1) rs += __shfl_xor(rs, mm);
        lrow[r] = lrow[r] * scale + rs;
        mrow[r] = mnew;
#pragma unroll
        for (int f = 0; f < 4; f++) o[f][r] *= scale;
      }

#pragma unroll
      for (int kf = 0; kf < 4; kf++)
#pragma unroll
        for (int r = 0; r < 4; r++)
          P_s[w][l4 * 4 + r][kf * 16 + l15] = (bf16)pvv[kf][r];

      bf16x8 pa0 = *(const bf16x8*)&P_s[w][l15][l4 * 8];
      bf16x8 pa1 = *(const bf16x8*)&P_s[w][l15][32 + l4 * 8];
#pragma unroll
      for (int f = 0; f < 4; f++) {
        const bf16* vp = &Vt[vtb + (size_t)(f * 16 + l15) * NPAD + vcol0];
        bf16x8 v0 = *(const bf16x8*)(vp + l4 * 8);
        bf16x8 v1 = *(const bf16x8*)(vp + 32 + l4 * 8);
        o[f] = __builtin_amdgcn_mfma_f32_16x16x32_bf16(pa0, v0, o[f], 0, 0, 0);
        o[f] = __builtin_amdgcn_mfma_f32_16x16x32_bf16(pa1, v1, o[f], 0, 0, 0);
      }
    }

    if (l4 == 0) {
#pragma unroll
      for (int f = 0; f < 4; f++)
#pragma unroll
        for (int r = 0; r < 4; r++) o_sf[(w * 4 + r) * 64 + f * 16 + l15] = o[f][r];
      if (l15 == 0)
#pragma unroll
        for (int r = 0; r < 4; r++) {
          ml_sf[(w * 2 + 0) * 16 + r] = mrow[r];
          ml_sf[(w * 2 + 1) * 16 + r] = lrow[r];
        }
    }
    __syncthreads();
    int row = tid >> 6, dim = tid & 63;
    float M = -1e30f;
#pragma unroll
    for (int ww = 0; ww < 4; ww++) M = fmaxf(M, ml_sf[(ww * 2) * 16 + row]);
    float L = 0.0f, val = 0.0f;
#pragma unroll
    for (int ww = 0; ww < 4; ww++) {
      float e = __expf(ml_sf[(ww * 2) * 16 + row] - M);
      L += e * ml_sf[(ww * 2 + 1) * 16 + row];
      val += e * o_sf[(ww * 4 + row) * 64 + dim];
    }
    att[((size_t)(b * NSEQ + row)) * CDIM + h * HD + dim] = (bf16)(val / L);
  }
}

// ------------------------------------------------------------------------
extern "C" void kernel_launch(void* const* d_in, const int* in_sizes, int n_in,
                              void* d_out, int out_size, void* d_ws, size_t ws_size,
                              hipStream_t stream) {
  const float* hidden = (const float*)d_in[0];
  const float* cosb = (const float*)d_in[1];
  const float* sinb = (const float*)d_in[2];
  const float* qkv_w = (const float*)d_in[3];
  const float* out_w = (const float*)d_in[4];
  const float* norm_q_w = (const float*)d_in[5];
  const float* norm_k_w = (const float*)d_in[6];
  const int* win = (const int*)d_in[7];
  float* out = (float*)d_out;

  char* ws = (char*)d_ws;
  size_t off = 0;
  auto alloc = [&](size_t bytes) {
    char* p = ws + off;
    off += (bytes + 255) & ~(size_t)255;
    return p;
  };
  bf16* A_bf  = (bf16*)alloc((size_t)M_REAL * CDIM * 2);
  bf16* W1    = (bf16*)alloc((size_t)3 * CDIM * CDIM * 2);
  bf16* W2    = (bf16*)alloc((size_t)CDIM * CDIM * 2);
  bf16* v_raw = (bf16*)alloc((size_t)BHN * NSEQ * HD * 2);
  bf16* q_bf  = (bf16*)alloc((size_t)BHN * NPAD * HD * 2);
  bf16* k_bf  = (bf16*)alloc((size_t)BHN * NPAD * HD * 2);
  bf16* vT    = (bf16*)alloc((size_t)BHN * HD * NPAD * 2);
  bf16* att   = (bf16*)alloc((size_t)M_REAL * CDIM * 2);
  (void)ws_size; (void)in_sizes; (void)n_in; (void)out_size;

  cast3_kernel<<<2048, 256, 0, stream>>>(
      hidden, A_bf, (long)M_REAL * CDIM,
      qkv_w, W1, (long)3 * CDIM * CDIM,
      out_w, W2, (long)CDIM * CDIM);

  // GEMM1 (exact R12): 792 blocks, BN=128, DEPTH=1; W1 strip L2-pinned/XCD.
  gemm_bf16_kernel<0, 3, 128, 1><<<792, 256, 0, stream>>>(
      A_bf, W1, q_bf, k_bf, v_raw, nullptr, cosb, sinb, norm_q_w, norm_k_w);
  v_transpose_kernel<<<dim3(17, 64), 256, 0, stream>>>(v_raw, vT);
  // attn (R18 + slim specials phase): 17 x 64 = 1088 blocks.
  attn_kernel<<<dim3(17, 64), 256, 0, stream>>>(q_bf, k_bf, vT, att, win);
  // GEMM2 (exact R12): 528 blocks, BN=64, DEPTH=1; W2 strip L2-pinned/XCD.
  gemm_bf16_kernel<1, 2, 64, 1><<<528, 256, 0, stream>>>(
      att, W2, nullptr, nullptr, nullptr, out, nullptr, nullptr, nullptr, nullptr);
}